// Round 1
// 596.831 us; speedup vs baseline: 1.1030x; 1.1030x over previous
//
#include <hip/hip_runtime.h>
#include <math.h>

#define BB 4
#define TT 4
#define CC 256
#define HH 30
#define WW 40
#define HWS (HH*WW)          // 1200
#define CHW (CC*HWS)         // 307200
#define CHW4 (CHW/4)

typedef __attribute__((ext_vector_type(8))) _Float16 half8;
typedef __attribute__((ext_vector_type(4))) float f32x4;

// ---------------------------------------------------------------------------
// h0 = sum_t x[b,t,:,:,:]; c0 = h0   (float4 vectorized)
// ---------------------------------------------------------------------------
__global__ void init_hc(const float* __restrict__ x,
                        float* __restrict__ h, float* __restrict__ c) {
    int id = blockIdx.x * 256 + threadIdx.x;
    if (id >= BB * CHW4) return;
    int b = id / CHW4;
    int rem = id - b * CHW4;
    const f32x4* xv = (const f32x4*)x;
    f32x4 s = {0.f, 0.f, 0.f, 0.f};
#pragma unroll
    for (int t = 0; t < TT; ++t)
        s += xv[((size_t)b * TT + t) * CHW4 + rem];
    ((f32x4*)h)[id] = s;
    ((f32x4*)c)[id] = s;
}

// ---------------------------------------------------------------------------
// Pack weights to f16: layout [kg=k/8][Cout][k%8]
// k = (src? 2304:0) + tap*256 + ci  over K=4608
// ---------------------------------------------------------------------------
__global__ void pack_weights(const float* __restrict__ W1,
                             const float* __restrict__ W2,
                             _Float16* __restrict__ wt, int Cout) {
    int idx = blockIdx.x * 256 + threadIdx.x;
    if (idx >= 4608 * Cout) return;
    int k = idx / Cout;
    int n = idx - k * Cout;
    float v = (k < 2304) ? W1[(size_t)k * Cout + n]
                         : W2[(size_t)(k - 2304) * Cout + n];
    wt[((size_t)(k >> 3) * Cout + n) * 8 + (k & 7)] = (_Float16)v;
}

// ---------------------------------------------------------------------------
// MFMA dual 3x3 conv, f16, K-split over blockIdx.z (NZ chunks per source):
//   src = z/NZ (0 -> in0*scale, 1 -> in1), ci range = (z%NZ)*(CC/NZ) .. +CC/NZ
//   z==0 partial additionally carries bias b1+b2.
// out has NZ*2 stacked [B,Cout,H,W] buffers (z selects).
// Pipelined schedule: double-buffered LDS act tile, one barrier per K-iter,
// stage loads issued one iter ahead (write landed mid-compute), 4-slot rolling
// weight register prefetch (~3-tap distance covers L2 latency).
// ---------------------------------------------------------------------------
template<int NW, int NZ>
__global__ __launch_bounds__(256, 3) void conv_mfma(
    const float* __restrict__ in0, long bs0, const float* __restrict__ scale,
    const float* __restrict__ in1, long bs1,
    const _Float16* __restrict__ wt,
    const float* __restrict__ b1, const float* __restrict__ b2,
    float* __restrict__ out, int Cout)
{
    constexpr int NK = 8 / NZ;                      // K-iters (32 ci each)
    __shared__ alignas(16) _Float16 s_a[2][4 * 168 * 8];

    const int tid = threadIdx.x;
    const int l = tid & 63, wv = tid >> 6;
    const int q = l >> 4, r = l & 15;
    const int mb = blockIdx.x;                      // 0..59
    const int b = mb / 15;
    const int pix0 = (mb % 15) * 80;
    const int y0 = (mb % 15) * 2;
    const int n0 = blockIdx.y * (4 * NW * 16) + wv * (NW * 16);
    const int z = blockIdx.z;
    const int src = z / NZ;
    const int ci_start = (z % NZ) * (CC / NZ);
    const int kgb0 = src * 288 + (ci_start >> 3);

    const float* inp = (src ? in1 + (size_t)b * bs1 : in0 + (size_t)b * bs0)
                       + (size_t)ci_start * HWS;
    const float* scl = (src == 0) ? scale : nullptr;

    // ---- per-thread staging geometry (3 items, fixed across K-loop) ----
    bool iv[3], pv[3];
    const float* pj[3];
    float sc[3];
    int ldsoff[3];
#pragma unroll
    for (int j = 0; j < 3; ++j) {
        int item = tid + j * 256;
        iv[j] = item < 672;
        int it = iv[j] ? item : 0;
        int cig = it / 168;
        int pix = it - cig * 168;
        int row = pix / 42;
        int px = pix - row * 42;
        int xx = px - 1, yy = y0 + row - 1;
        pv[j] = iv[j] && xx >= 0 && xx < WW && yy >= 0 && yy < HH;
        pj[j] = inp + (size_t)(cig * 8) * HWS + yy * WW + xx;
        sc[j] = 1.f;
        if (scl && pv[j]) sc[j] = scl[(size_t)b * HWS + yy * WW + xx];
        ldsoff[j] = (cig * 168 + pix) * 8;
    }

    // ---- accumulators (bias folded into z==0 partial) ----
    f32x4 acc[5][NW];
#pragma unroll
    for (int nt = 0; nt < NW; ++nt) {
        int co = n0 + nt * 16 + r;
        float bias = (z == 0) ? (b1[co] + b2[co]) : 0.f;
        f32x4 bv = {bias, bias, bias, bias};
#pragma unroll
        for (int mt = 0; mt < 5; ++mt) acc[mt][nt] = bv;
    }

    // ---- per-mt LDS pixel base (fold tap offset into ds_read immediate) ----
    int hbase[5];
#pragma unroll
    for (int mt = 0; mt < 5; ++mt) {
        int p = mt * 16 + r;
        int ry = p / 40;
        int rx = p - ry * 40;
        hbase[mt] = ry * 42 + rx;
    }

    // ---- staging pipeline: issue-early (before barrier), write-late ----
    float sr[3][8];
    auto stage_issue = [&](int kk) {
#pragma unroll
        for (int j = 0; j < 3; ++j) if (pv[j]) {
            const float* p0 = pj[j] + (size_t)kk * 32 * HWS;
#pragma unroll
            for (int t = 0; t < 8; ++t) sr[j][t] = p0[(size_t)t * HWS];
        }
    };
    auto stage_write = [&](int kk) {
#pragma unroll
        for (int j = 0; j < 3; ++j) if (iv[j]) {
            half8 hv = {0, 0, 0, 0, 0, 0, 0, 0};
            if (pv[j]) {
#pragma unroll
                for (int t = 0; t < 8; ++t)
                    hv[t] = (_Float16)(sr[j][t] * sc[j]);
            }
            *(half8*)&s_a[kk & 1][ldsoff[j]] = hv;
        }
    };

    const half8* wp = (const half8*)wt;
    half8 w0[NW], w1[NW], w2[NW], w3[NW];

#define WLOAD(SLOT, TAP) do {                                              \
    const int kg_ = kgb0 + k * 4 + (TAP) * 32 + q;                         \
    _Pragma("unroll")                                                      \
    for (int nt = 0; nt < NW; ++nt)                                        \
        SLOT[nt] = wp[(size_t)kg_ * Cout + n0 + nt * 16 + r];              \
} while (0)

#define CTAP(SLOT, TAP) do {                                               \
    constexpr int dy_ = (TAP) / 3, dx_ = (TAP) % 3;                        \
    _Pragma("unroll")                                                      \
    for (int mt = 0; mt < 5; ++mt) {                                       \
        half8 af = *(const half8*)&s_a[k & 1]                              \
            [(q * 168 + hbase[mt] + dy_ * 42 + dx_) * 8];                  \
        _Pragma("unroll")                                                  \
        for (int nt = 0; nt < NW; ++nt)                                    \
            acc[mt][nt] = __builtin_amdgcn_mfma_f32_16x16x32_f16(          \
                af, SLOT[nt], acc[mt][nt], 0, 0, 0);                       \
    }                                                                      \
} while (0)

    // prologue: stage tile 0
    stage_issue(0);
    stage_write(0);

#pragma unroll
    for (int k = 0; k < NK; ++k) {
        WLOAD(w0, 0); WLOAD(w1, 1); WLOAD(w2, 2);    // taps 0-2, fly over barrier
        if (k + 1 < NK) stage_issue(k + 1);          // next act tile, fly over compute
        __syncthreads();                             // s_a[k&1] ready
        __builtin_amdgcn_s_setprio(1);
        WLOAD(w3, 3); CTAP(w0, 0);
        WLOAD(w0, 4); CTAP(w1, 1);
        WLOAD(w1, 5); CTAP(w2, 2);
        WLOAD(w2, 6); CTAP(w3, 3);
        WLOAD(w3, 7); CTAP(w0, 4);
        WLOAD(w0, 8); CTAP(w1, 5);
        __builtin_amdgcn_s_setprio(0);
        if (k + 1 < NK) stage_write(k + 1);          // land next tile mid-compute
        __builtin_amdgcn_s_setprio(1);
        CTAP(w2, 6);
        CTAP(w3, 7);
        CTAP(w0, 8);
        __builtin_amdgcn_s_setprio(0);
    }
#undef WLOAD
#undef CTAP

    out += (size_t)z * BB * Cout * HWS;
#pragma unroll
    for (int mt = 0; mt < 5; ++mt) {
#pragma unroll
        for (int nt = 0; nt < NW; ++nt) {
            int co = n0 + nt * 16 + r;
            int p = pix0 + mt * 16 + q * 4;
            *(f32x4*)&out[((size_t)b * Cout + co) * HWS + p] = acc[mt][nt];
        }
    }
}

// ---------------------------------------------------------------------------
// att = tanh(a0 + a1 + a2 + a3)  (4 stacked K-split partials, float4 loads)
// ---------------------------------------------------------------------------
__global__ void add_tanh4(const float* __restrict__ a0,
                          float* __restrict__ o, int n4) {
    int id = blockIdx.x * 256 + threadIdx.x;
    if (id >= n4) return;
    const f32x4* av = (const f32x4*)a0;
    f32x4 s = av[id] + av[id + (size_t)n4] + av[id + 2 * (size_t)n4]
            + av[id + 3 * (size_t)n4];
    f32x4 rr;
#pragma unroll
    for (int j = 0; j < 4; ++j) rr[j] = tanhf(s[j]);
    ((f32x4*)o)[id] = rr;
}

// ---------------------------------------------------------------------------
// K-split attention score: part[b][ch][p] = sum_{ca in chunk ch} sum_tap
//   att[b,ca,y+dy-1,x+dx-1] * Va[tap,ca]
// ---------------------------------------------------------------------------
__global__ __launch_bounds__(256) void att_e_part(
    const float* __restrict__ att, const float* __restrict__ Va,
    float* __restrict__ part)
{
    __shared__ float red[4][64];
    const int lane = threadIdx.x & 63, wv = threadIdx.x >> 6;
    const int p = blockIdx.x * 64 + lane;
    const int b = blockIdx.y, ch = blockIdx.z;
    const bool valid = (p < HWS);
    const int pc = valid ? p : 0;
    const int y = pc / WW, x = pc - (pc / WW) * WW;

    float acc = 0.f;
    if (valid) {
        const int ca0 = ch * 32 + wv * 8;
#pragma unroll
        for (int j = 0; j < 8; ++j) {
            const int ca = ca0 + j;
            const float* base = att + ((size_t)b * CC + ca) * HWS;
            const float* va = Va + ca;
#pragma unroll
            for (int dy = 0; dy < 3; ++dy) {
                int yy = y + dy - 1;
                if (yy < 0 || yy >= HH) continue;
#pragma unroll
                for (int dx = 0; dx < 3; ++dx) {
                    int xx = x + dx - 1;
                    if (xx < 0 || xx >= WW) continue;
                    acc = fmaf(base[yy * WW + xx], va[(dy * 3 + dx) * CC], acc);
                }
            }
        }
    }
    red[wv][lane] = acc;
    __syncthreads();
    if (wv == 0 && valid)
        part[((size_t)b * 8 + ch) * HWS + p] =
            red[0][lane] + red[1][lane] + red[2][lane] + red[3][lane];
}

// ---------------------------------------------------------------------------
// softmax over HW per batch, summing the 8 K-split partials first (in LDS)
// ---------------------------------------------------------------------------
__global__ __launch_bounds__(256) void softmax_kernel(
    const float* __restrict__ part, float* __restrict__ a)
{
    __shared__ float se[HWS];
    __shared__ float red[256];
    int b = blockIdx.x;
    int tid = threadIdx.x;

    for (int i = tid; i < HWS; i += 256) {
        float s = 0.f;
#pragma unroll
        for (int ch = 0; ch < 8; ++ch)
            s += part[((size_t)b * 8 + ch) * HWS + i];
        se[i] = s;
    }
    __syncthreads();

    float m = -1e30f;
    for (int i = tid; i < HWS; i += 256) m = fmaxf(m, se[i]);
    red[tid] = m;
    __syncthreads();
    for (int s = 128; s > 0; s >>= 1) {
        if (tid < s) red[tid] = fmaxf(red[tid], red[tid + s]);
        __syncthreads();
    }
    m = red[0];
    __syncthreads();

    float sum = 0.f;
    for (int i = tid; i < HWS; i += 256) {
        float v = expf(se[i] - m);
        se[i] = v;
        sum += v;
    }
    red[tid] = sum;
    __syncthreads();
    for (int s = 128; s > 0; s >>= 1) {
        if (tid < s) red[tid] += red[tid + s];
        __syncthreads();
    }
    float inv = 1.f / red[0];
    for (int i = tid; i < HWS; i += 256)
        a[(size_t)b * HWS + i] = se[i] * inv;
}

// ---------------------------------------------------------------------------
// LSTM gate update, fusing the K-split partial sum: g = g0 + g1 (float4)
// ---------------------------------------------------------------------------
__global__ void gate_update(const float* __restrict__ g0, const float* __restrict__ g1,
                            float* __restrict__ c, float* __restrict__ h_out) {
    int id = blockIdx.x * 256 + threadIdx.x;
    if (id >= BB * CHW4) return;
    int b = id / CHW4;
    int rem = id - b * CHW4;
    const f32x4* g0v = (const f32x4*)g0;
    const f32x4* g1v = (const f32x4*)g1;
    size_t gb = (size_t)b * 4 * CHW4 + rem;
    f32x4 gi = g0v[gb] + g1v[gb];
    f32x4 gf = g0v[gb + CHW4] + g1v[gb + CHW4];
    f32x4 gc = g0v[gb + 2 * (size_t)CHW4] + g1v[gb + 2 * (size_t)CHW4];
    f32x4 go = g0v[gb + 3 * (size_t)CHW4] + g1v[gb + 3 * (size_t)CHW4];
    f32x4 cv = ((const f32x4*)c)[id];
    f32x4 cn, hn;
#pragma unroll
    for (int j = 0; j < 4; ++j) {
        float i_ = 1.f / (1.f + expf(-gi[j]));
        float f_ = 1.f / (1.f + expf(-gf[j]));
        float o_ = 1.f / (1.f + expf(-go[j]));
        float cc = f_ * cv[j] + i_ * tanhf(gc[j]);
        cn[j] = cc;
        hn[j] = o_ * tanhf(cc);
    }
    ((f32x4*)c)[id] = cn;
    ((f32x4*)h_out)[id] = hn;
}

// ---------------------------------------------------------------------------
extern "C" void kernel_launch(void* const* d_in, const int* in_sizes, int n_in,
                              void* d_out, int out_size, void* d_ws, size_t ws_size,
                              hipStream_t stream) {
    const float* x   = (const float*)d_in[0];
    const float* Wa  = (const float*)d_in[1];
    const float* ba  = (const float*)d_in[2];
    const float* Ua  = (const float*)d_in[3];
    const float* bua = (const float*)d_in[4];
    const float* Va  = (const float*)d_in[5];
    const float* Wx  = (const float*)d_in[6];
    const float* bx  = (const float*)d_in[7];
    const float* Uh  = (const float*)d_in[8];
    const float* bh  = (const float*)d_in[9];
    float* out = (float*)d_out;

    char* wsb = (char*)d_ws;
    const size_t NCHW = (size_t)BB * CHW;
    _Float16* wtg = (_Float16*)wsb;               wsb += (size_t)4608 * 1024 * 2;
    _Float16* wta = (_Float16*)wsb;               wsb += (size_t)4608 * 256 * 2;
    float* h0   = (float*)wsb;                    wsb += NCHW * 4;
    float* h1   = (float*)wsb;                    wsb += NCHW * 4;
    float* cb   = (float*)wsb;                    wsb += NCHW * 4;
    float* g01  = (float*)wsb;                    wsb += 8 * NCHW * 4;   // z-stacked
    float* att  = (float*)wsb;                    wsb += NCHW * 4;
    float* part = (float*)wsb;                    wsb += (size_t)BB * 8 * HWS * 4;
    float* a    = (float*)wsb;
    // att01 (4 z-stacked partials) aliases g01: lifetimes are disjoint
    // within a timestep (att01 dead after add_tanh4, g01 born at conv<2>).
    float* att01 = g01;

    pack_weights<<<dim3((4608 * 1024 + 255) / 256), dim3(256), 0, stream>>>(
        Wx, Uh, wtg, 1024);
    pack_weights<<<dim3((4608 * 256 + 255) / 256), dim3(256), 0, stream>>>(
        Wa, Ua, wta, 256);

    const int n4 = BB * CHW4;
    init_hc<<<dim3((n4 + 255) / 256), dim3(256), 0, stream>>>(x, h0, cb);

    float* hbuf[2] = {h0, h1};
    const long XT_BS = (long)TT * CHW;
    const long H_BS  = (long)CHW;

    for (int t = 0; t < TT; ++t) {
        const float* xt = x + (size_t)t * CHW;
        float* hcur = hbuf[t & 1];
        float* hnext = (t == TT - 1) ? out : hbuf[(t + 1) & 1];

        // attention partials: z in {0,1}: conv(h, Wa) ci-halves (z=0 carries bias)
        //                     z in {2,3}: conv(xt, Ua) ci-halves
        conv_mfma<1, 2><<<dim3(60, 4, 4), dim3(256), 0, stream>>>(
            hcur, H_BS, nullptr, xt, XT_BS, wta, ba, bua, att01, 256);
        add_tanh4<<<dim3((n4 + 255) / 256), dim3(256), 0, stream>>>(
            att01, att, n4);

        // e-partials (K-split over ca) + softmax (sums partials)
        att_e_part<<<dim3(19, BB, 8), dim3(256), 0, stream>>>(att, Va, part);
        softmax_kernel<<<dim3(BB), dim3(256), 0, stream>>>(part, a);

        // gates: g01[z=0] = conv(xt*a, Wx)+bx+bh ; g01[z=1] = conv(h, Uh)
        conv_mfma<2, 1><<<dim3(60, 8, 2), dim3(256), 0, stream>>>(
            xt, XT_BS, a, hcur, H_BS, wtg, bx, bh, g01, 1024);

        gate_update<<<dim3((n4 + 255) / 256), dim3(256), 0, stream>>>(
            g01, g01 + 4 * NCHW, cb, hnext);
    }
}